// Round 11
// baseline (285.222 us; speedup 1.0000x reference)
//
#include <hip/hip_runtime.h>
#include <math.h>

#define NV 8192
#define NE 4096
#define DIN 512
#define DH 256
#define CAP_E 96
#define CAP_V 64
#define NPROJ (NV / 32)      // 256 proj-GEMM blocks
#define NCOMP (NV / 2)       // 4096 compress blocks (2 rows/block, pure stream)

// ---------------- workspace layout (float offsets) ----------------
#define OFF_XH   0                       // V*DH fp32 (residual)
#define OFF_UB   (OFF_XH + NV*DH)        // V*DH bf16 (U = Xh@W^T)
#define OFF_YB   (OFF_UB + NV*DH/2)      // E*DH bf16
#define OFF_NCNT (OFF_YB + NE*DH/2)      // V ints
#define OFF_ECNT (OFF_NCNT + NV)         // E*16 ints (line-padded counters)
#define OFF_EL   (OFF_ECNT + NE*16)      // E*CAP_E ints
#define OFF_NL   (OFF_EL + NE*CAP_E)     // V*CAP_V ints
#define OFF_XHB  (OFF_NL + NV*CAP_V)     // V*DH bf16 (layer-0 LN out, feeds gemm_u)
#define OFF_Q    (OFF_XHB + NV*DH/2)     // V float2: per-node classifier dots
#define OFF_BITS (OFF_Q + NV*2)          // V*64 u64 bitmasks (4 MB)

using bf16x8 = __attribute__((ext_vector_type(8))) short;
using f32x4  = __attribute__((ext_vector_type(4))) float;
using f32x4v = __attribute__((ext_vector_type(4))) float;
typedef unsigned long long u64;

__device__ inline unsigned short f2bf(float f) {   // round-to-nearest-even
    union { float f; unsigned u; } v; v.f = f;
    unsigned r = v.u + 0x7FFF + ((v.u >> 16) & 1);
    return (unsigned short)(r >> 16);
}
__device__ inline float b2f(unsigned short s) {
    union { unsigned u; float f; } v; v.u = ((unsigned)s) << 16; return v.f;
}

// ---- U-GEMM from an LDS-stashed 32x256 bf16 A-tile (verified rounds 4-10) ----
__device__ inline void u_gemm_from_lds(const short* __restrict__ sm,
                                       const float* __restrict__ W,
                                       unsigned short* __restrict__ Ub,
                                       int bm, int tid) {
    const int w = tid >> 6, lane = tid & 63;
    const int r15 = lane & 15, k8 = (lane >> 4) << 3;
    const int swz = lane ^ ((lane >> 3) & 6);
    f32x4 acc[2][4];
#pragma unroll
    for (int mi = 0; mi < 2; ++mi)
#pragma unroll
        for (int ni = 0; ni < 4; ++ni) acc[mi][ni] = (f32x4){0.f, 0.f, 0.f, 0.f};
#pragma unroll
    for (int kc = 0; kc < 8; ++kc) {
        bf16x8 af[2], bfr[4];
        af[0] = *(const bf16x8*)&sm[(0 * 8 + kc) * 512 + swz * 8];
        af[1] = *(const bf16x8*)&sm[(1 * 8 + kc) * 512 + swz * 8];
#pragma unroll
        for (int ni = 0; ni < 4; ++ni) {
            const float* wr = W + (size_t)(w * 64 + ni * 16 + r15) * DH + kc * 32 + k8;
            float4 b0 = *(const float4*)wr;
            float4 b1 = *(const float4*)(wr + 4);
            bf16x8 bv;
            bv[0] = (short)f2bf(b0.x); bv[1] = (short)f2bf(b0.y);
            bv[2] = (short)f2bf(b0.z); bv[3] = (short)f2bf(b0.w);
            bv[4] = (short)f2bf(b1.x); bv[5] = (short)f2bf(b1.y);
            bv[6] = (short)f2bf(b1.z); bv[7] = (short)f2bf(b1.w);
            bfr[ni] = bv;
        }
#pragma unroll
        for (int mi = 0; mi < 2; ++mi)
#pragma unroll
            for (int ni = 0; ni < 4; ++ni)
                acc[mi][ni] = __builtin_amdgcn_mfma_f32_16x16x32_bf16(
                    af[mi], bfr[ni], acc[mi][ni], 0, 0, 0);
    }
    const int quad = lane >> 4, cl = lane & 15;
#pragma unroll
    for (int mi = 0; mi < 2; ++mi)
#pragma unroll
        for (int ni = 0; ni < 4; ++ni)
#pragma unroll
            for (int r = 0; r < 4; ++r)
                Ub[(size_t)(bm + mi * 16 + quad * 4 + r) * DH + w * 64 + ni * 16 + cl]
                    = f2bf(acc[mi][ni][r]);
}

// ---- fused: blocks [0,NPROJ) proj GEMM + U0 (verbatim);
//      blocks [NPROJ, NPROJ+NCOMP): pure-stream COMPRESS of H into bitmasks.
//      2 rows/block, coalesced 1KB loads, __ballot packing, NO atomics —
//      decouples the 134MB stream from list-building so it runs at HBM rate. ----
__global__ __launch_bounds__(256) void compress_proj(const float* __restrict__ H,
                                                     const float* __restrict__ X,
                                                     const float* __restrict__ Wp,
                                                     const float* __restrict__ W0,
                                                     float* __restrict__ Xh,
                                                     unsigned short* __restrict__ Ub,
                                                     u64* __restrict__ bits) {
    __shared__ short AsBs[1024 + 8192];
    const int tid = threadIdx.x;
    if (blockIdx.x >= NPROJ) {
        const int w = tid >> 6, lane = tid & 63;
        const int vb = (blockIdx.x - NPROJ) * 2;
        const f32x4v* H4 = (const f32x4v*)(H + (size_t)vb * NE);
        f32x4v h[2][4];
#pragma unroll
        for (int r = 0; r < 2; ++r)
#pragma unroll
            for (int it = 0; it < 4; ++it)
                h[r][it] = __builtin_nontemporal_load(&H4[r * 1024 + tid + it * 256]);
        // pack: word (w*16 + it*4 + c), bit l  <->  col 4*(w*64 + l + it*256) + c
        u64 myword[2] = {0ULL, 0ULL};
#pragma unroll
        for (int r = 0; r < 2; ++r)
#pragma unroll
            for (int it = 0; it < 4; ++it)
#pragma unroll
                for (int c = 0; c < 4; ++c) {
                    u64 b = __ballot(h[r][it][c] != 0.0f);
                    if (lane == it * 4 + c) myword[r] = b;
                }
        if (lane < 16) {
            bits[(size_t)vb * 64 + w * 16 + lane]       = myword[0];
            bits[(size_t)(vb + 1) * 64 + w * 16 + lane] = myword[1];
        }
        return;
    }
    // ---------------- proj GEMM path (round-10 verbatim) ----------------
    short* As = AsBs;
    short* Bs = AsBs + 1024;
    const int K = DIN;
    const int lane = tid & 63;
    const int w    = tid >> 6;
    const int bm   = blockIdx.x * 32;
    const int swz  = lane ^ ((lane >> 3) & 6);
    float4 ar, br[8];
    ar = *(const float4*)(X + (size_t)(bm + (tid >> 3)) * K + ((tid & 7) << 2));
#pragma unroll
    for (int it = 0; it < 8; ++it) {
        int i = tid + it * 256;
        br[it] = *(const float4*)(Wp + (size_t)(i >> 3) * K + ((i & 7) << 2));
    }
    f32x4 acc[2][4];
#pragma unroll
    for (int mi = 0; mi < 2; ++mi)
#pragma unroll
        for (int ni = 0; ni < 4; ++ni) acc[mi][ni] = (f32x4){0.f, 0.f, 0.f, 0.f};
    for (int k0 = 0; k0 < K; k0 += 32) {
        __syncthreads();
        {
            int row = tid >> 3, kk = (tid & 7) << 2;
            int quad = kk >> 3, j = kk & 7;
            int ln = (row & 15) + (quad << 4);
            int pp = ln ^ ((ln >> 3) & 6);
            ushort4 u = {f2bf(ar.x), f2bf(ar.y), f2bf(ar.z), f2bf(ar.w)};
            *(ushort4*)&As[(row >> 4) * 512 + pp * 8 + j] = u;
        }
#pragma unroll
        for (int it = 0; it < 8; ++it) {
            int i = tid + it * 256;
            int row = i >> 3, kk = (i & 7) << 2;
            int quad = kk >> 3, j = kk & 7;
            int ln = (row & 15) + (quad << 4);
            int pp = ln ^ ((ln >> 3) & 6);
            float4 v = br[it];
            ushort4 u = {f2bf(v.x), f2bf(v.y), f2bf(v.z), f2bf(v.w)};
            *(ushort4*)&Bs[(row >> 4) * 512 + pp * 8 + j] = u;
        }
        __syncthreads();
        if (k0 + 32 < K) {
            int kn = k0 + 32;
            ar = *(const float4*)(X + (size_t)(bm + (tid >> 3)) * K + kn + ((tid & 7) << 2));
#pragma unroll
            for (int it = 0; it < 8; ++it) {
                int i = tid + it * 256;
                br[it] = *(const float4*)(Wp + (size_t)(i >> 3) * K + kn + ((i & 7) << 2));
            }
        }
        bf16x8 af[2], bfr[4];
        af[0] = *(const bf16x8*)&As[0 * 512 + swz * 8];
        af[1] = *(const bf16x8*)&As[1 * 512 + swz * 8];
#pragma unroll
        for (int ni = 0; ni < 4; ++ni)
            bfr[ni] = *(const bf16x8*)&Bs[(w * 4 + ni) * 512 + swz * 8];
#pragma unroll
        for (int mi = 0; mi < 2; ++mi)
#pragma unroll
            for (int ni = 0; ni < 4; ++ni)
                acc[mi][ni] = __builtin_amdgcn_mfma_f32_16x16x32_bf16(
                    af[mi], bfr[ni], acc[mi][ni], 0, 0, 0);
    }
    const int quad = lane >> 4, cl = lane & 15;
    __syncthreads();
#pragma unroll
    for (int mi = 0; mi < 2; ++mi)
#pragma unroll
        for (int ni = 0; ni < 4; ++ni)
#pragma unroll
            for (int r = 0; r < 4; ++r) {
                float v = acc[mi][ni][r];
                int rl  = mi * 16 + quad * 4 + r;
                int col = w * 64 + ni * 16 + cl;
                Xh[(size_t)(bm + rl) * DH + col] = v;
                int kc = col >> 5, kk = col & 31;
                int q2 = kk >> 3, j = kk & 7;
                int ln = (rl & 15) + (q2 << 4);
                int pp = ln ^ ((ln >> 3) & 6);
                AsBs[(mi * 8 + kc) * 512 + pp * 8 + j] = (short)f2bf(v);
            }
    __syncthreads();
    u_gemm_from_lds(AsBs, W0, Ub, bm, tid);
}

// ---- list build from bitmasks: wave/row, lane/u64-word. Reads 4MB (LLC-hot),
//      short per-lane chains (~0.26 set bits/lane), tiny VGPR, full occupancy. ----
__global__ __launch_bounds__(256) void build_lists(const u64* __restrict__ bits,
                                                   int* __restrict__ edge_cnt,
                                                   int* __restrict__ node_cnt,
                                                   int* __restrict__ edge_list,
                                                   int* __restrict__ node_list) {
    const int tid = threadIdx.x;
    const int w = tid >> 6, lane = tid & 63;
    const int v = blockIdx.x * 4 + w;
    u64 m = bits[(size_t)v * 64 + lane];
    int n = __builtin_popcountll(m);
    int pre = n;
#pragma unroll
    for (int o = 1; o < 64; o <<= 1) {
        int t = __shfl_up(pre, o, 64);
        if (lane >= o) pre += t;
    }
    int total = __shfl(pre, 63, 64);
    if (lane == 0) node_cnt[v] = total;      // plain store: one wave owns the row
    int base = pre - n;
    // decode: word lane = w2*16 + it*4 + c; bit l -> col 4*(w2*64 + l + it*256) + c
    const int w2 = lane >> 4, r = lane & 15, it = r >> 2, c = r & 3;
    const int cbase = 4 * (w2 * 64 + it * 256) + c;
    int k = 0;
    while (m) {
        int l = __builtin_ctzll(m); m &= m - 1;
        int e = cbase + 4 * l;
        int gc = atomicAdd(&edge_cnt[e << 4], 1);
        if (gc < CAP_E) edge_list[e * CAP_E + gc] = v;
        int idx = base + k;
        if (idx < CAP_V) node_list[v * CAP_V + idx] = e;
        ++k;
    }
}

// ------- gemm_u (round-0 verbatim) -------
__global__ __launch_bounds__(256) void gemm_u(const unsigned short* __restrict__ A,
                                              const float* __restrict__ W,
                                              unsigned short* __restrict__ U) {
    const int K = DH;
    __shared__ short As[2048];
    __shared__ short Bs[16384];
    const int tid  = threadIdx.x;
    const int lane = tid & 63;
    const int w    = tid >> 6;
    const int bm   = blockIdx.x * 32;
    const int swz  = lane ^ ((lane >> 3) & 6);

    uint4 ar; float4 br[16];
    ar = *(const uint4*)(A + (size_t)(bm + (tid >> 3)) * K + ((tid & 7) << 3));
#pragma unroll
    for (int it = 0; it < 16; ++it) {
        int i = tid + it * 256;
        br[it] = *(const float4*)(W + (size_t)(i >> 4) * K + ((i & 15) << 2));
    }
    f32x4 acc[2][4];
#pragma unroll
    for (int mi = 0; mi < 2; ++mi)
#pragma unroll
        for (int ni = 0; ni < 4; ++ni) acc[mi][ni] = (f32x4){0.f, 0.f, 0.f, 0.f};

    for (int k0 = 0; k0 < K; k0 += 64) {
        __syncthreads();
        {
            int row = tid >> 3, kq = tid & 7;
            int kc = kq >> 2, quad = kq & 3;
            int ln = (row & 15) + (quad << 4);
            int pp = ln ^ ((ln >> 3) & 6);
            *(uint4*)&As[((row >> 4) * 2 + kc) * 512 + pp * 8] = ar;
        }
#pragma unroll
        for (int it = 0; it < 16; ++it) {
            int i = tid + it * 256;
            int row = i >> 4, kk = (i & 15) << 2;
            int kc = kk >> 5, quad = (kk >> 3) & 3, j = kk & 7;
            int ln = (row & 15) + (quad << 4);
            int pp = ln ^ ((ln >> 3) & 6);
            float4 v = br[it];
            ushort4 u = {f2bf(v.x), f2bf(v.y), f2bf(v.z), f2bf(v.w)};
            *(ushort4*)&Bs[((row >> 4) * 2 + kc) * 512 + pp * 8 + j] = u;
        }
        __syncthreads();
        if (k0 + 64 < K) {
            int kn = k0 + 64;
            ar = *(const uint4*)(A + (size_t)(bm + (tid >> 3)) * K + kn + ((tid & 7) << 3));
#pragma unroll
            for (int it = 0; it < 16; ++it) {
                int i = tid + it * 256;
                br[it] = *(const float4*)(W + (size_t)(i >> 4) * K + kn + ((i & 15) << 2));
            }
        }
#pragma unroll
        for (int kc = 0; kc < 2; ++kc) {
            bf16x8 af[2], bfr[4];
            af[0] = *(const bf16x8*)&As[(0 * 2 + kc) * 512 + swz * 8];
            af[1] = *(const bf16x8*)&As[(1 * 2 + kc) * 512 + swz * 8];
#pragma unroll
            for (int ni = 0; ni < 4; ++ni)
                bfr[ni] = *(const bf16x8*)&Bs[((w * 4 + ni) * 2 + kc) * 512 + swz * 8];
#pragma unroll
            for (int mi = 0; mi < 2; ++mi)
#pragma unroll
                for (int ni = 0; ni < 4; ++ni)
                    acc[mi][ni] = __builtin_amdgcn_mfma_f32_16x16x32_bf16(
                        af[mi], bfr[ni], acc[mi][ni], 0, 0, 0);
        }
    }
    const int quad = lane >> 4, cl = lane & 15;
#pragma unroll
    for (int mi = 0; mi < 2; ++mi)
#pragma unroll
        for (int ni = 0; ni < 4; ++ni)
#pragma unroll
            for (int r = 0; r < 4; ++r)
                U[(size_t)(bm + mi * 16 + quad * 4 + r) * DH + w * 64 + ni * 16 + cl]
                    = f2bf(acc[mi][ni][r]);
}

// ---- Yb[e,:] = bf16( rsqrt(de) * sum_{v in e} rsqrt(dv) * Ub[v,:] ) (round-0 verbatim) ----
__global__ __launch_bounds__(64) void edge_gather(const unsigned short* __restrict__ Ub,
                                                  const int* __restrict__ edge_cnt,
                                                  const int* __restrict__ edge_list,
                                                  const int* __restrict__ node_cnt,
                                                  unsigned short* __restrict__ Yb) {
    int e = blockIdx.x;
    int tid = threadIdx.x;
    __shared__ int   lv[CAP_E];
    __shared__ float lc[CAP_E];
    int tc = edge_cnt[e << 4];
    int cnt = min(tc, CAP_E);
    for (int j = tid; j < cnt; j += 64) {
        int v = edge_list[e * CAP_E + j];
        lv[j] = v * (DH / 4);
        lc[j] = rsqrtf((float)node_cnt[v]);
    }
    __syncthreads();
    const ushort4* X4 = (const ushort4*)Ub;
    float4 a[8];
#pragma unroll
    for (int u = 0; u < 8; ++u) a[u] = (float4){0.f, 0.f, 0.f, 0.f};
    int i = 0;
    for (; i + 8 <= cnt; i += 8) {
#pragma unroll
        for (int u = 0; u < 8; ++u) {
            ushort4 h = X4[lv[i + u] + tid]; float c = lc[i + u];
            a[u].x = fmaf(c, b2f(h.x), a[u].x); a[u].y = fmaf(c, b2f(h.y), a[u].y);
            a[u].z = fmaf(c, b2f(h.z), a[u].z); a[u].w = fmaf(c, b2f(h.w), a[u].w);
        }
    }
    for (; i < cnt; ++i) {
        ushort4 h = X4[lv[i] + tid]; float c = lc[i];
        a[0].x = fmaf(c, b2f(h.x), a[0].x); a[0].y = fmaf(c, b2f(h.y), a[0].y);
        a[0].z = fmaf(c, b2f(h.z), a[0].z); a[0].w = fmaf(c, b2f(h.w), a[0].w);
    }
#pragma unroll
    for (int u = 4; u > 0; u >>= 1)
#pragma unroll
        for (int q = 0; q < u; ++q) {
            a[q].x += a[q + u].x; a[q].y += a[q + u].y;
            a[q].z += a[q + u].z; a[q].w += a[q + u].w;
        }
    float de = tc > 0 ? rsqrtf((float)tc) : 0.f;
    ushort4 o = {f2bf(de * a[0].x), f2bf(de * a[0].y),
                 f2bf(de * a[0].z), f2bf(de * a[0].w)};
    ((ushort4*)Yb)[e * (DH / 4) + tid] = o;
}

// ---- layer-0 node gather + relu + residual + LayerNorm (round-0 verbatim) ----
__global__ __launch_bounds__(64) void node_ln(const unsigned short* __restrict__ Yb,
                                              const int* __restrict__ node_cnt,
                                              const int* __restrict__ node_list,
                                              const int* __restrict__ edge_cnt,
                                              float* __restrict__ Xh,
                                              unsigned short* __restrict__ Xhb,
                                              const float* __restrict__ g,
                                              const float* __restrict__ b) {
    int v = blockIdx.x;
    int tid = threadIdx.x;
    __shared__ int   le[CAP_V];
    __shared__ float lc[CAP_V];
    int tc = node_cnt[v];
    int cnt = min(tc, CAP_V);
    if (tid < cnt) {
        int e = node_list[v * CAP_V + tid];
        le[tid] = e * (DH / 4);
        lc[tid] = rsqrtf((float)edge_cnt[e << 4]);
    }
    __syncthreads();
    const ushort4* Y4 = (const ushort4*)Yb;
    float4 a[8];
#pragma unroll
    for (int u = 0; u < 8; ++u) a[u] = (float4){0.f, 0.f, 0.f, 0.f};
    int i = 0;
    for (; i + 8 <= cnt; i += 8) {
#pragma unroll
        for (int u = 0; u < 8; ++u) {
            ushort4 h = Y4[le[i + u] + tid]; float c = lc[i + u];
            a[u].x = fmaf(c, b2f(h.x), a[u].x); a[u].y = fmaf(c, b2f(h.y), a[u].y);
            a[u].z = fmaf(c, b2f(h.z), a[u].z); a[u].w = fmaf(c, b2f(h.w), a[u].w);
        }
    }
    for (; i < cnt; ++i) {
        ushort4 h = Y4[le[i] + tid]; float c = lc[i];
        a[0].x = fmaf(c, b2f(h.x), a[0].x); a[0].y = fmaf(c, b2f(h.y), a[0].y);
        a[0].z = fmaf(c, b2f(h.z), a[0].z); a[0].w = fmaf(c, b2f(h.w), a[0].w);
    }
#pragma unroll
    for (int u = 4; u > 0; u >>= 1)
#pragma unroll
        for (int q = 0; q < u; ++q) {
            a[q].x += a[q + u].x; a[q].y += a[q + u].y;
            a[q].z += a[q + u].z; a[q].w += a[q + u].w;
        }
    float dv = tc > 0 ? rsqrtf((float)tc) : 0.f;
    float4 xr = ((const float4*)Xh)[v * (DH / 4) + tid];
    float x0 = xr.x + fmaxf(dv * a[0].x, 0.f);
    float x1 = xr.y + fmaxf(dv * a[0].y, 0.f);
    float x2 = xr.z + fmaxf(dv * a[0].z, 0.f);
    float x3 = xr.w + fmaxf(dv * a[0].w, 0.f);
    float s = (x0 + x1) + (x2 + x3);
    float q = fmaf(x0, x0, fmaf(x1, x1, fmaf(x2, x2, x3 * x3)));
#pragma unroll
    for (int o = 1; o < 64; o <<= 1) {
        s += __shfl_xor(s, o, 64);
        q += __shfl_xor(q, o, 64);
    }
    float m = s * (1.0f / DH);
    float var = q * (1.0f / DH) - m * m;
    float rstd = rsqrtf(var + 1e-5f);
    float4 g4 = ((const float4*)g)[tid];
    float4 b4 = ((const float4*)b)[tid];
    float4 o;
    o.x = (x0 - m) * rstd * g4.x + b4.x;
    o.y = (x1 - m) * rstd * g4.y + b4.y;
    o.z = (x2 - m) * rstd * g4.z + b4.z;
    o.w = (x3 - m) * rstd * g4.w + b4.w;
    ((float4*)Xh)[v * (DH / 4) + tid] = o;
    ushort4 ob = {f2bf(o.x), f2bf(o.y), f2bf(o.z), f2bf(o.w)};
    ((ushort4*)Xhb)[v * (DH / 4) + tid] = ob;
}

// ---- layer-1 node gather + LN + fused per-node classifier dot (round-9 verbatim) ----
__global__ __launch_bounds__(64) void node_ln_q(const unsigned short* __restrict__ Yb,
                                                const int* __restrict__ node_cnt,
                                                const int* __restrict__ node_list,
                                                const int* __restrict__ edge_cnt,
                                                const float* __restrict__ Xh,
                                                const float* __restrict__ g,
                                                const float* __restrict__ b,
                                                const float* __restrict__ Wc,
                                                float2* __restrict__ qout) {
    int v = blockIdx.x;
    int tid = threadIdx.x;
    __shared__ int   le[CAP_V];
    __shared__ float lc[CAP_V];
    int tc = node_cnt[v];
    int cnt = min(tc, CAP_V);
    if (tid < cnt) {
        int e = node_list[v * CAP_V + tid];
        le[tid] = e * (DH / 4);
        lc[tid] = rsqrtf((float)edge_cnt[e << 4]);
    }
    __syncthreads();
    const ushort4* Y4 = (const ushort4*)Yb;
    float4 a[8];
#pragma unroll
    for (int u = 0; u < 8; ++u) a[u] = (float4){0.f, 0.f, 0.f, 0.f};
    int i = 0;
    for (; i + 8 <= cnt; i += 8) {
#pragma unroll
        for (int u = 0; u < 8; ++u) {
            ushort4 h = Y4[le[i + u] + tid]; float c = lc[i + u];
            a[u].x = fmaf(c, b2f(h.x), a[u].x); a[u].y = fmaf(c, b2f(h.y), a[u].y);
            a[u].z = fmaf(c, b2f(h.z), a[u].z); a[u].w = fmaf(c, b2f(h.w), a[u].w);
        }
    }
    for (; i < cnt; ++i) {
        ushort4 h = Y4[le[i] + tid]; float c = lc[i];
        a[0].x = fmaf(c, b2f(h.x), a[0].x); a[0].y = fmaf(c, b2f(h.y), a[0].y);
        a[0].z = fmaf(c, b2f(h.z), a[0].z); a[0].w = fmaf(c, b2f(h.w), a[0].w);
    }
#pragma unroll
    for (int u = 4; u > 0; u >>= 1)
#pragma unroll
        for (int q = 0; q < u; ++q) {
            a[q].x += a[q + u].x; a[q].y += a[q + u].y;
            a[q].z += a[q + u].z; a[q].w += a[q + u].w;
        }
    float dv = tc > 0 ? rsqrtf((float)tc) : 0.f;
    float4 xr = ((const float4*)Xh)[v * (DH / 4) + tid];
    float x0 = xr.x + fmaxf(dv * a[0].x, 0.f);
    float x1 = xr.y + fmaxf(dv * a[0].y, 0.f);
    float x2 = xr.z + fmaxf(dv * a[0].z, 0.f);
    float x3 = xr.w + fmaxf(dv * a[0].w, 0.f);
    float s = (x0 + x1) + (x2 + x3);
    float q = fmaf(x0, x0, fmaf(x1, x1, fmaf(x2, x2, x3 * x3)));
#pragma unroll
    for (int o = 1; o < 64; o <<= 1) {
        s += __shfl_xor(s, o, 64);
        q += __shfl_xor(q, o, 64);
    }
    float m = s * (1.0f / DH);
    float var = q * (1.0f / DH) - m * m;
    float rstd = rsqrtf(var + 1e-5f);
    float4 g4 = ((const float4*)g)[tid];
    float4 b4 = ((const float4*)b)[tid];
    float o0 = b2f(f2bf((x0 - m) * rstd * g4.x + b4.x));
    float o1 = b2f(f2bf((x1 - m) * rstd * g4.y + b4.y));
    float o2 = b2f(f2bf((x2 - m) * rstd * g4.z + b4.z));
    float o3 = b2f(f2bf((x3 - m) * rstd * g4.w + b4.w));
    const float4* W4 = (const float4*)Wc;
    float4 w0 = W4[tid], w1 = W4[64 + tid];
    float p0 = o0 * w0.x + o1 * w0.y + o2 * w0.z + o3 * w0.w;
    float p1 = o0 * w1.x + o1 * w1.y + o2 * w1.z + o3 * w1.w;
#pragma unroll
    for (int off = 32; off > 0; off >>= 1) {
        p0 += __shfl_down(p0, off, 64);
        p1 += __shfl_down(p1, off, 64);
    }
    if (tid == 0) qout[v] = make_float2(p0, p1);
}

// ------- pool on per-node scalars (round-9 verbatim) -------
__global__ __launch_bounds__(256) void pool_q(const float2* __restrict__ q,
                                              const int* __restrict__ edge_cnt,
                                              const int* __restrict__ edge_list,
                                              const float* __restrict__ bc,
                                              float* __restrict__ out) {
    const int tid = threadIdx.x;
    const int w = tid >> 6, lane = tid & 63;
    const int e = blockIdx.x * 4 + w;
    int tc = edge_cnt[e << 4];
    int cnt = min(tc, CAP_E);
    float s0 = 0.f, s1 = 0.f;
    for (int j = lane; j < cnt; j += 64) {
        int v = edge_list[e * CAP_E + j];
        float2 qq = q[v];
        s0 += qq.x; s1 += qq.y;
    }
#pragma unroll
    for (int o = 32; o > 0; o >>= 1) {
        s0 += __shfl_down(s0, o, 64);
        s1 += __shfl_down(s1, o, 64);
    }
    if (lane == 0) {
        float inv = tc > 0 ? 1.0f / (float)tc : 1.0f;
        float l0 = s0 * inv + bc[0], l1 = s1 * inv + bc[1];
        float mx = fmaxf(l0, l1);
        float e0 = expf(l0 - mx), e1 = expf(l1 - mx);
        float sden = 1.0f / (e0 + e1);
        out[e * 2 + 0] = e0 * sden;
        out[e * 2 + 1] = e1 * sden;
    }
}

extern "C" void kernel_launch(void* const* d_in, const int* in_sizes, int n_in,
                              void* d_out, int out_size, void* d_ws, size_t ws_size,
                              hipStream_t stream) {
    const float* X  = (const float*)d_in[0];
    const float* H  = (const float*)d_in[1];
    const float* Wp = (const float*)d_in[2];
    const float* W0 = (const float*)d_in[3];
    const float* W1 = (const float*)d_in[4];
    const float* g0 = (const float*)d_in[5];
    const float* b0 = (const float*)d_in[6];
    const float* g1 = (const float*)d_in[7];
    const float* b1 = (const float*)d_in[8];
    const float* Wc = (const float*)d_in[9];
    const float* bc = (const float*)d_in[10];
    float* out = (float*)d_out;

    float* ws = (float*)d_ws;
    float* Xh  = ws + OFF_XH;
    unsigned short* Ub  = (unsigned short*)(ws + OFF_UB);
    unsigned short* Yb  = (unsigned short*)(ws + OFF_YB);
    int* node_cnt  = (int*)(ws + OFF_NCNT);
    int* edge_cnt  = (int*)(ws + OFF_ECNT);
    int* edge_list = (int*)(ws + OFF_EL);
    int* node_list = (int*)(ws + OFF_NL);
    unsigned short* Xhb = (unsigned short*)(ws + OFF_XHB);
    float2* qbuf = (float2*)(ws + OFF_Q);
    u64* bits = (u64*)(ws + OFF_BITS);

    // node_cnt and edge_cnt are contiguous: one memset for both
    hipMemsetAsync(node_cnt, 0, (size_t)(NV + NE * 16) * sizeof(int), stream);

    // stage A1: proj GEMM + fused U0 | pure-stream H compress (no atomics)
    compress_proj<<<NPROJ + NCOMP, 256, 0, stream>>>(H, X, Wp, W0, Xh, Ub, bits);
    // stage A2: list build from 4MB of bitmasks (LLC-hot, short chains)
    build_lists<<<NV / 4, 256, 0, stream>>>(bits, edge_cnt, node_cnt,
                                            edge_list, node_list);

    // layer 0 (U0 already in Ub)
    edge_gather<<<NE, 64, 0, stream>>>(Ub, edge_cnt, edge_list, node_cnt, Yb);
    node_ln<<<NV, 64, 0, stream>>>(Yb, node_cnt, node_list, edge_cnt,
                                   Xh, Xhb, g0, b0);
    // layer 1 (U1 from standalone high-occupancy gemm_u)
    gemm_u<<<NV / 32, 256, 0, stream>>>(Xhb, W1, Ub);
    edge_gather<<<NE, 64, 0, stream>>>(Ub, edge_cnt, edge_list, node_cnt, Yb);
    node_ln_q<<<NV, 64, 0, stream>>>(Yb, node_cnt, node_list, edge_cnt,
                                     Xh, g1, b1, Wc, qbuf);

    // pool on 8-byte per-node scalars
    pool_q<<<NE / 4, 256, 0, stream>>>(qbuf, edge_cnt, edge_list, bc, out);
}